// Round 1
// baseline (144.742 us; speedup 1.0000x reference)
//
#include <hip/hip_runtime.h>
#include <hip/hip_bf16.h>

// Problem constants (fixed by the reference generator).
constexpr int E      = 2048;   // edges
constexpr int NVARS  = 512;    // variable nodes
constexpr int MAXF   = 24;     // max fan-in per edge (deg-1; binomial(256,1/64) max ~14)
constexpr int TB     = 4;      // batch rows per block in main kernel

// ---------------------------------------------------------------------------
// Kernel 1: build sparse tables from the dense masks (runs every launch;
// deterministic: compaction order == row order via ballot/popcount).
//   srcs [MAXF][E] : source edge index per (slot, out-edge)
//   ws   [MAXF][E] : fused weight = mask * odd_weight * dropout_gate
//   cnts [E]       : fan-in per out-edge
//   vars_[E]       : variable node feeding edge e
//   skw  [E]       : fused skip weight = mask * llr_weight
// One wave (64 threads) per output edge column e.
// ---------------------------------------------------------------------------
__global__ __launch_bounds__(64)
void build_tables(const float* __restrict__ u,
                  const float* __restrict__ odd_w,
                  const float* __restrict__ logits,
                  const float* __restrict__ o2e_mask,
                  const float* __restrict__ skip_mask,
                  const float* __restrict__ llr_w,
                  int*   __restrict__ srcs,
                  float* __restrict__ ws,
                  int*   __restrict__ cnts,
                  int*   __restrict__ vars_,
                  float* __restrict__ skw)
{
    const int e    = blockIdx.x;
    const int lane = threadIdx.x;          // 0..63

    int cnt = 0;
    for (int it = 0; it < E / 64; ++it) {
        const int row = it * 64 + lane;
        const float m = o2e_mask[(size_t)row * E + e];
        const bool nz = (m != 0.0f);
        const unsigned long long bal = __ballot(nz);
        if (nz) {
            const int pos = cnt + __popcll(bal & ((1ull << lane) - 1ull));
            if (pos < MAXF) {
                const float l   = logits[row];
                const float sig = 1.0f / (1.0f + __expf(-l));
                const float z   = (u[row] < sig) ? 1.0f : 0.0f;
                srcs[(size_t)pos * E + e] = row;
                ws  [(size_t)pos * E + e] = m * odd_w[(size_t)row * E + e] * z;
            }
        }
        cnt += __popcll(bal);
    }
    if (lane == 0) cnts[e] = (cnt < MAXF) ? cnt : MAXF;

    // Skip connection: exactly one nonzero per column of skip_mask.
    for (int it = 0; it < NVARS / 64; ++it) {
        const int v = it * 64 + lane;
        const float m = skip_mask[(size_t)v * E + e];
        if (m != 0.0f) {
            vars_[e] = v;
            skw [e]  = m * llr_w[(size_t)v * E + e];
        }
    }
}

// tanh(0.5*clip(s,-10,10)) = (e^c - 1)/(e^c + 1), c = clamped s.
__device__ __forceinline__ float tanh_half_clip(float s) {
    float c = fminf(fmaxf(s, -10.0f), 10.0f);
    float t = __expf(c);
    return (t - 1.0f) * __frcp_rn(t + 1.0f);
}

// ---------------------------------------------------------------------------
// Kernel 2: fused sparse gather + skip + tanh.
// Block: 256 threads, TB=4 batch rows, all E edges.
// ---------------------------------------------------------------------------
__global__ __launch_bounds__(256)
void fused_main(const float* __restrict__ x,     // [B, E]
                const float* __restrict__ llr,   // [B, NVARS]
                const int*   __restrict__ srcs,
                const float* __restrict__ ws,
                const int*   __restrict__ cnts,
                const int*   __restrict__ vars_,
                const float* __restrict__ skw,
                float* __restrict__ out)
{
    __shared__ float xs[TB][E];
    __shared__ float ls[TB][NVARS];

    const int b0 = blockIdx.x * TB;
    const int t  = threadIdx.x;

    // Stage x rows (TB*E = 8192 floats = 2048 float4; 8 per thread, coalesced).
    const float4* xg  = (const float4*)(x + (size_t)b0 * E);
    float4*       xsv = (float4*)&xs[0][0];
    #pragma unroll
    for (int i = 0; i < (TB * E / 4) / 256; ++i)
        xsv[i * 256 + t] = xg[i * 256 + t];

    // Stage llr rows (TB*NVARS = 2048 floats = 512 float4; 2 per thread).
    const float4* lg  = (const float4*)(llr + (size_t)b0 * NVARS);
    float4*       lsv = (float4*)&ls[0][0];
    #pragma unroll
    for (int i = 0; i < (TB * NVARS / 4) / 256; ++i)
        lsv[i * 256 + t] = lg[i * 256 + t];

    __syncthreads();

    #pragma unroll
    for (int k = 0; k < E / 256; ++k) {
        const int e   = k * 256 + t;           // consecutive e across threads
        const int cnt = cnts[e];
        const int v   = vars_[e];
        const float sv = skw[e];

        float acc0 = sv * ls[0][v];
        float acc1 = sv * ls[1][v];
        float acc2 = sv * ls[2][v];
        float acc3 = sv * ls[3][v];

        for (int j = 0; j < cnt; ++j) {
            const int   s = srcs[(size_t)j * E + e];   // coalesced across threads
            const float w = ws  [(size_t)j * E + e];
            acc0 += w * xs[0][s];
            acc1 += w * xs[1][s];
            acc2 += w * xs[2][s];
            acc3 += w * xs[3][s];
        }

        const size_t o = (size_t)b0 * E + e;
        out[o]         = tanh_half_clip(acc0);
        out[o + E]     = tanh_half_clip(acc1);
        out[o + 2 * E] = tanh_half_clip(acc2);
        out[o + 3 * E] = tanh_half_clip(acc3);
    }
}

extern "C" void kernel_launch(void* const* d_in, const int* in_sizes, int n_in,
                              void* d_out, int out_size, void* d_ws, size_t ws_size,
                              hipStream_t stream) {
    const float* x        = (const float*)d_in[0];  // [B, E]
    const float* llr      = (const float*)d_in[1];  // [B, NVARS]
    const float* u        = (const float*)d_in[2];  // [E]
    const float* odd_w    = (const float*)d_in[3];  // [E, E]
    const float* llr_w    = (const float*)d_in[4];  // [NVARS, E]
    const float* logits   = (const float*)d_in[5];  // [E]
    const float* o2e_mask = (const float*)d_in[6];  // [E, E]
    const float* skip_msk = (const float*)d_in[7];  // [NVARS, E]
    float* out = (float*)d_out;

    const int B = in_sizes[0] / E;                  // 16384

    // Workspace layout (all 4-byte aligned; total ~408 KB).
    char* wsb = (char*)d_ws;
    int*   srcs  = (int*)  (wsb);
    float* wsw   = (float*)(wsb + (size_t)MAXF * E * 4);
    int*   cnts  = (int*)  (wsb + (size_t)2 * MAXF * E * 4);
    int*   vars_ = (int*)  (wsb + (size_t)2 * MAXF * E * 4 + (size_t)E * 4);
    float* skw   = (float*)(wsb + (size_t)2 * MAXF * E * 4 + (size_t)2 * E * 4);

    build_tables<<<dim3(E), dim3(64), 0, stream>>>(
        u, odd_w, logits, o2e_mask, skip_msk, llr_w,
        srcs, wsw, cnts, vars_, skw);

    fused_main<<<dim3(B / TB), dim3(256), 0, stream>>>(
        x, llr, srcs, wsw, cnts, vars_, skw, out);
}